// Round 3
// baseline (155.183 us; speedup 1.0000x reference)
//
#include <hip/hip_runtime.h>

// 16-qubit variational-circuit simulator, B=128, re/im split into independent
// real states. Convention (proven): qubit q <-> global flat bit (15-q);
// out[b][i] = <Z on qubit 15-i> accumulated from |amp|^2 signs.
//
// P0 (512 blocks x 1024 thr, 16 reals/thread): locals q0..13, grid = b,c,v(q14).
//   thread map: m(4b regs)<->q0..3 (m bit i <-> q(3-i)); lane(6b)<->q4..9
//   (lane bit i <-> q(9-i)); w(4b)<->q10..13 (w bit i <-> q(13-i)).
//   Light cone: RY_k for q <= 15-k; CZ_k pairs q in [0,14-k].
//   Store s = (m<<10)|(w<<6)|lane, i.e. s = [q0..q3 | q10..q13 | q4..q9].
// P1 (8192 blocks x 512 thr, 4 reals/thread): block fixes (b, Qa=q0..3, Qb=q4,q5);
//   thread: c=tid8, y=tid[7:6] (y1=q6,y0=q7), lane<->q8..13 (lane bit i <-> q(13-i)),
//   regs m'=(v=q14)<<1|(h=q15). Applies RY_k for q >= 16-k; CZ_k pairs [15-k,14].

#define DEV __device__ __forceinline__

DEV float2 cmul(float2 a, float2 b) {
    return make_float2(a.x * b.x - a.y * b.y, a.x * b.y + a.y * b.x);
}

DEV float dpp_xor1(float x) {  // lane ^ 1 via quad_perm [1,0,3,2]
    return __int_as_float(__builtin_amdgcn_update_dpp(0, __float_as_int(x), 0xB1, 0xF, 0xF, false));
}
DEV float dpp_xor2(float x) {  // lane ^ 2 via quad_perm [2,3,0,1]
    return __int_as_float(__builtin_amdgcn_update_dpp(0, __float_as_int(x), 0x4E, 0xF, 0xF, false));
}

// ---------------- precompute tables ----------------
__global__ void qsim_pre(const float* __restrict__ x, const float* __restrict__ theta,
                         float2* __restrict__ tsc, float4* __restrict__ psit) {
    const int t = blockIdx.x * 256 + threadIdx.x;
    if (t < 128) {
        float S, C; sincosf(0.5f * theta[t], &S, &C);
        tsc[t] = make_float2(C, S);
    }
    if (t < 2048) {
        const int b = t >> 4, q = t & 15;
        float sa, ca, SA, CA;
        sincosf(0.5f * x[b * 16 + q], &sa, &ca);
        sincosf(0.5f * theta[q], &SA, &CA);
        psit[t] = make_float4(CA * ca, SA * sa, SA * ca, -CA * sa);
    }
}

// ---------------- P0 ----------------
__global__ __launch_bounds__(1024, 8) void qsim_p0(const float4* __restrict__ psit,
                                                   const float2* __restrict__ tsc,
                                                   float* __restrict__ st) {
    const int bx = blockIdx.x;
    const int b = bx >> 2, v = (bx >> 1) & 1, c = bx & 1;
    const int tid = threadIdx.x;
    const int lane = tid & 63, w = tid >> 6;

    __shared__ float X[8][1024];  // 32 KB exchange

    // ---- product init through RY1 ----
    const float4* pb = psit + b * 16;
    float2 common = make_float2(1.f, 0.f);
#pragma unroll
    for (int q = 4; q <= 9; ++q) {
        float4 p = pb[q];
        int bit = (lane >> (9 - q)) & 1;
        common = cmul(common, bit ? make_float2(p.z, p.w) : make_float2(p.x, p.y));
    }
#pragma unroll
    for (int q = 10; q <= 13; ++q) {
        float4 p = pb[q];
        int bit = (w >> (13 - q)) & 1;
        common = cmul(common, bit ? make_float2(p.z, p.w) : make_float2(p.x, p.y));
    }
    {
        float4 p = pb[14];
        common = cmul(common, v ? make_float2(p.z, p.w) : make_float2(p.x, p.y));
    }
    float2 ps0[4], ps1[4];
#pragma unroll
    for (int q = 0; q < 4; ++q) {
        float4 p = pb[q];
        ps0[q] = make_float2(p.x, p.y);
        ps1[q] = make_float2(p.z, p.w);
    }

    float a[16];
#pragma unroll
    for (int m = 0; m < 16; ++m) {
        float2 prod = common;
#pragma unroll
        for (int q = 0; q < 4; ++q) {
            int bit = (m >> (3 - q)) & 1;
            prod = cmul(prod, bit ? ps1[q] : ps0[q]);
        }
        a[m] = c ? prod.y : prod.x;
    }

    // ---- CZ sign machinery ----
    // Pairs (q0,q1),(q1,q2),(q2,q3),(q3,q4): per-amp mask over m (always included).
    unsigned Pm = 0;
    const int l5 = (lane >> 5) & 1;  // q4
#pragma unroll
    for (int m = 0; m < 16; ++m) {
        int m0 = m & 1, m1 = (m >> 1) & 1, m2 = (m >> 2) & 1, m3 = (m >> 3) & 1;
        int pm = ((m3 & m2) ^ (m2 & m1) ^ (m1 & m0) ^ (m0 & l5)) & 1;
        Pm |= ((unsigned)pm) << m;
    }
    // Thread-fixed pairs q in [4,13]: A bit z <-> q(14-z); AA bit t <-> pair q=13-t.
    const unsigned A = ((unsigned)lane << 5) | ((unsigned)w << 1) | (unsigned)v;
    const unsigned AA = (A & (A >> 1)) & 0x3FFu;

    auto czP0 = [&](int k) {  // pairs q in [0,14-k] => AA bits t >= k-1, plus Pm
        unsigned T = __popc(AA >> (k - 1)) & 1u;
        unsigned Wm = T ? (Pm ^ 0xFFFFu) : Pm;
#pragma unroll
        for (int m = 0; m < 16; ++m) {
            unsigned sg = ((Wm >> m) & 1u) << 31;
            a[m] = __uint_as_float(__float_as_uint(a[m]) ^ sg);
        }
    };

    czP0(1);

    for (int k = 2; k <= 8; ++k) {
        // reg gates q=0..3 (always applied)
#pragma unroll
        for (int q = 0; q < 4; ++q) {
            float2 cs = tsc[(k - 1) * 16 + q];
            const float C = cs.x, S = cs.y;
            const int mb = 1 << (3 - q);
#pragma unroll
            for (int m = 0; m < 16; ++m)
                if (!(m & mb)) {
                    float t0 = a[m], t1 = a[m | mb];
                    a[m]      = C * t0 - S * t1;
                    a[m | mb] = S * t0 + C * t1;
                }
        }
        // lane gates q=4..9, guarded by light cone (uniform branch, static masks)
#pragma unroll
        for (int q = 4; q <= 9; ++q) {
            if (q <= 15 - k) {
                float2 cs = tsc[(k - 1) * 16 + q];
                const float C = cs.x, S = cs.y;
                const int lb = 9 - q;
                const float Sg = ((lane >> lb) & 1) ? S : -S;
#pragma unroll
                for (int i = 0; i < 16; ++i) {
                    float p;
                    if (lb == 0)      p = dpp_xor1(a[i]);
                    else if (lb == 1) p = dpp_xor2(a[i]);
                    else              p = __shfl_xor(a[i], 1 << lb);
                    a[i] = C * a[i] + Sg * p;
                }
            }
        }
        // wave gates q=10..13 via LDS (two 8-reg chunks)
#pragma unroll
        for (int q = 10; q <= 13; ++q) {
            if (q <= 15 - k) {
                float2 cs = tsc[(k - 1) * 16 + q];
                const float C = cs.x, S = cs.y;
                const int wb = 13 - q;
                const int pt = tid ^ (64 << wb);
                const float Sg = ((w >> wb) & 1) ? S : -S;
#pragma unroll
                for (int h = 0; h < 2; ++h) {
                    __syncthreads();
#pragma unroll
                    for (int i = 0; i < 8; ++i) X[i][tid] = a[h * 8 + i];
                    __syncthreads();
#pragma unroll
                    for (int i = 0; i < 8; ++i) {
                        float p = X[i][pt];
                        a[h * 8 + i] = C * a[h * 8 + i] + Sg * p;
                    }
                }
            }
        }
        czP0(k);
    }

    // coalesced store: s = (m<<10) | tid
    float* outp = st + (((size_t)(b * 2 + c)) << 15) + ((size_t)v << 14);
#pragma unroll
    for (int m = 0; m < 16; ++m) outp[(m << 10) | tid] = a[m];
}

// ---------------- P1 ----------------
__global__ __launch_bounds__(512, 8) void qsim_p1(const float4* __restrict__ psit,
                                                  const float2* __restrict__ tsc,
                                                  const float* __restrict__ st,
                                                  float* __restrict__ partials) {
    const int blk = blockIdx.x;
    const int b = blk >> 6;
    const int Qa = (blk >> 2) & 15, Qb = blk & 3, Qf = blk & 63;
    const int tid = threadIdx.x;
    const int lane = tid & 63;
    const int Wp = tid >> 6;                    // [c, y1, y0]
    const int c = (Wp >> 2) & 1, y1 = (Wp >> 1) & 1, y0 = Wp & 1;

    __shared__ float L[1024];   // [cin(1)|v(1)|u(4)|t(4)]
    __shared__ float red[8][9];

    const size_t sbase = ((size_t)b << 16);
#pragma unroll
    for (int j = 0; j < 2; ++j) {
        int flat = j * 512 + tid;
        int cin = (flat >> 9) & 1, vv = (flat >> 8) & 1;
        int u = (flat >> 4) & 15, t = flat & 15;
        L[flat] = st[sbase + ((size_t)cin << 15) + (vv << 14) + (Qa << 10) + (u << 6) + (Qb << 4) + t];
    }
    __syncthreads();

    const float4 p15 = psit[b * 16 + 15];
    const int ut = lane & 15;                                   // [q10..q13]
    const int tt = (y1 << 3) | (y0 << 2) | (((lane >> 5) & 1) << 1) | ((lane >> 4) & 1);  // [q6,q7,q8,q9]

    float a[4];   // m' = (v<<1)|h ; bit0 = q15, bit1 = q14
#pragma unroll
    for (int vv = 0; vv < 2; ++vv) {
        float sre = L[(0 << 9) | (vv << 8) | (ut << 4) | tt];
        float sim = L[(1 << 9) | (vv << 8) | (ut << 4) | tt];
#pragma unroll
        for (int h = 0; h < 2; ++h) {
            float cr = h ? p15.z : p15.x;
            float ci = h ? p15.w : p15.y;
            a[(vv << 1) | h] = (c == 0) ? (cr * sre - ci * sim) : (cr * sim + ci * sre);
        }
    }

    // CZ remainder: pairs q in [15-k,14] <=> global nn bits t in [0,k-1], t = 14-q.
    const int l0 = lane & 1;
    unsigned PMa = 0, PMb = 0;
#pragma unroll
    for (int m = 0; m < 4; ++m) {
        int h = m & 1, vv2 = (m >> 1) & 1;
        PMa |= ((unsigned)(h & vv2)) << m;                       // t=0 only (k=1)
        PMb |= ((unsigned)((h & vv2) ^ (vv2 & l0))) << m;        // t=0,1 (k>=2)
    }
    const unsigned TT = ((unsigned)(lane & (lane >> 1)) & 0x1Fu) |
                        ((unsigned)((((lane >> 5) & 1) & y0)) << 5);  // t=2..7

    auto czP1 = [&](int k) {
        unsigned Wm;
        if (k == 1) Wm = PMa;
        else {
            unsigned T = __popc(TT & ((1u << (k - 2)) - 1u)) & 1u;
            Wm = T ? (PMb ^ 0xFu) : PMb;
        }
#pragma unroll
        for (int m = 0; m < 4; ++m) {
            unsigned sg = ((Wm >> m) & 1u) << 31;
            a[m] = __uint_as_float(__float_as_uint(a[m]) ^ sg);
        }
    };

    czP1(1);
    for (int k = 2; k <= 8; ++k) {
        {   // flat bit 0 = q15
            float2 cs = tsc[(k - 1) * 16 + 15];
            const float C = cs.x, S = cs.y;
            { float t0 = a[0], t1 = a[1]; a[0] = C * t0 - S * t1; a[1] = S * t0 + C * t1; }
            { float t0 = a[2], t1 = a[3]; a[2] = C * t0 - S * t1; a[3] = S * t0 + C * t1; }
        }
        {   // flat bit 1 = q14
            float2 cs = tsc[(k - 1) * 16 + 14];
            const float C = cs.x, S = cs.y;
            { float t0 = a[0], t1 = a[2]; a[0] = C * t0 - S * t1; a[2] = S * t0 + C * t1; }
            { float t0 = a[1], t1 = a[3]; a[1] = C * t0 - S * t1; a[3] = S * t0 + C * t1; }
        }
        // flat bits 2..7 = q13..q8, lane bit (B-2)
#pragma unroll
        for (int B = 2; B <= 7; ++B) {
            if (k >= B + 1) {
                float2 cs = tsc[(k - 1) * 16 + (15 - B)];
                const float C = cs.x, S = cs.y;
                const int lb = B - 2;
                const float Sg = ((lane >> lb) & 1) ? S : -S;
#pragma unroll
                for (int m = 0; m < 4; ++m) {
                    float p;
                    if (lb == 0)      p = dpp_xor1(a[m]);
                    else if (lb == 1) p = dpp_xor2(a[m]);
                    else              p = __shfl_xor(a[m], 1 << lb);
                    a[m] = C * a[m] + Sg * p;
                }
            }
        }
        czP1(k);
    }

    // ---- measurement ----
    float Ssum = 0.f, S1[2] = {0.f, 0.f};
#pragma unroll
    for (int m = 0; m < 4; ++m) {
        float pm = a[m] * a[m];
        Ssum += pm;
        if (m & 1) S1[0] += pm;
        if (m & 2) S1[1] += pm;
    }
    float P = Ssum, Bv[6];
#pragma unroll
    for (int d = 0; d < 6; ++d) {
        float t = __shfl_xor(P, 1 << d);
        Bv[d] = ((lane >> d) & 1) ? (t - P) : (P - t);
        P += t;
#pragma unroll
        for (int e = 0; e < 6; ++e)
            if (e < d) Bv[e] += __shfl_xor(Bv[e], 1 << d);
    }
#pragma unroll
    for (int i = 0; i < 2; ++i)
#pragma unroll
        for (int d = 0; d < 6; ++d) S1[i] += __shfl_xor(S1[i], 1 << d);

    if (lane == 0) {
        red[Wp][0] = P;
#pragma unroll
        for (int d = 0; d < 6; ++d) red[Wp][1 + d] = Bv[d];
        red[Wp][7] = S1[0];
        red[Wp][8] = S1[1];
    }
    __syncthreads();
    if (tid < 16) {
        const int i = tid;
        float r = 0.f;
#pragma unroll
        for (int Wt = 0; Wt < 8; ++Wt) {
            const float Av = red[Wt][0];
            if (i < 2)       r += Av - 2.f * red[Wt][7 + i];    // flat bits 0,1 (m')
            else if (i < 8)  r += red[Wt][i - 1];               // flat bits 2..7 (lane Walsh)
            else if (i == 8) r += (Wt & 1) ? -Av : Av;          // q7 = y0
            else if (i == 9) r += ((Wt >> 1) & 1) ? -Av : Av;   // q6 = y1
            else             r += Av;                           // block-fixed bits
        }
        if (i >= 10 && ((Qf >> (i - 10)) & 1)) r = -r;          // q5..q0 from block
        partials[(blk << 4) + i] = r;
    }
}

// ---------------- P2 ----------------
__global__ void qsim_p2(const float* __restrict__ partials, float* __restrict__ out) {
    const int idx = blockIdx.x * 256 + threadIdx.x;  // 2048 outputs
    if (idx < 2048) {
        const int b = idx >> 4, i = idx & 15;
        float s = 0.f;
#pragma unroll
        for (int g = 0; g < 64; ++g) s += partials[(((b << 6) | g) << 4) + i];
        out[idx] = s;
    }
}

extern "C" void kernel_launch(void* const* d_in, const int* in_sizes, int n_in,
                              void* d_out, int out_size, void* d_ws, size_t ws_size,
                              hipStream_t stream) {
    const float* x = (const float*)d_in[0];       // [128,16]
    const float* theta = (const float*)d_in[1];   // [128]
    float* out = (float*)d_out;                   // [128,16]
    float* ws = (float*)d_ws;
    float* st = ws;                               // 8388608 floats = 32 MiB
    float* partials = ws + 8388608;               // 131072 floats
    float2* tsc = (float2*)(ws + 8388608 + 131072);          // 128 float2
    float4* psit = (float4*)(ws + 8388608 + 131072 + 256);   // 2048 float4 (16B aligned)

    qsim_pre<<<8, 256, 0, stream>>>(x, theta, tsc, psit);
    qsim_p0<<<512, 1024, 0, stream>>>(psit, tsc, st);
    qsim_p1<<<8192, 512, 0, stream>>>(psit, tsc, st, partials);
    qsim_p2<<<8, 256, 0, stream>>>(partials, out);
}